// Round 16
// baseline (187.660 us; speedup 1.0000x reference)
//
#include <hip/hip_runtime.h>

typedef unsigned short u16;
typedef unsigned int u32;
typedef short short8 __attribute__((ext_vector_type(8)));
typedef float f32x4 __attribute__((ext_vector_type(4)));
typedef float f32x16 __attribute__((ext_vector_type(16)));
typedef float float4a __attribute__((ext_vector_type(4), aligned(4)));

#define NTOK 2009
#define M8   8036      // 4*2009 (real rows)
#define TOKP 2016      // padded tokens per batch (63*32)
#define M8P  8064      // 4*2016 padded rows
#define DMOD 1024
// packed fragment buffers: [bh][tile(63)][...][256] u16; 2048 u16 per tile
#define PKBH 129024    // 63*2048 u16 per bh

static __device__ __forceinline__ u16 f2bf(float f) {
  unsigned int x = __float_as_uint(f);
  x += 0x7fffu + ((x >> 16) & 1u);
  return (u16)(x >> 16);
}
static __device__ __forceinline__ float bf2f(u16 u) {
  return __uint_as_float((unsigned int)u << 16);
}
static __device__ __forceinline__ u32 pk2(float a, float b) {
  return (u32)f2bf(a) | ((u32)f2bf(b) << 16);
}
static __device__ __forceinline__ u32 cvtpk(float a, float b) {
  u32 d;
  asm("v_cvt_pk_bf16_f32 %0, %1, %2" : "=v"(d) : "v"(a), "v"(b));
  return d;
}
static __device__ __forceinline__ void gload_lds16(const void* g, void* l) {
  __builtin_amdgcn_global_load_lds(
      (const __attribute__((address_space(1))) void*)g,
      (__attribute__((address_space(3))) void*)l, 16, 0, 0);
}

// ---------------- merged converts (one launch); xb padded to [4][2016][1024] --
// x path: 2 float4 in -> 1 uint4 out per thread (16B stores).
__global__ void k_convs(const float* __restrict__ x, u16* __restrict__ xb,
                        const float* __restrict__ Wqkv, const float* __restrict__ Wqs,
                        u16* __restrict__ WtCat,
                        const float* __restrict__ Wout, u16* __restrict__ WtOut) {
  int blk = blockIdx.x;
  if (blk < 4032) {
    int i = blk * 256 + threadIdx.x;          // uint4 index over padded xb
    int b = i / (TOKP * 128);
    int rem = i - b * (TOKP * 128);
    int tok = rem >> 7, g8 = rem & 127;       // 8-float group within row
    uint4 o = make_uint4(0u, 0u, 0u, 0u);
    if (tok < NTOK) {
      const float4* src = (const float4*)x + (size_t)(b * NTOK + tok) * 256 + g8 * 2;
      float4 v0 = src[0], v1 = src[1];
      o.x = (u32)f2bf(v0.x) | ((u32)f2bf(v0.y) << 16);
      o.y = (u32)f2bf(v0.z) | ((u32)f2bf(v0.w) << 16);
      o.z = (u32)f2bf(v1.x) | ((u32)f2bf(v1.y) << 16);
      o.w = (u32)f2bf(v1.z) | ((u32)f2bf(v1.w) << 16);
    }
    ((uint4*)xb)[i] = o;
  } else if (blk < 4032 + 5120) {
    int i = (blk - 4032) * 256 + threadIdx.x;
    int n = i >> 10, k = i & 1023;
    float v = (n < 768) ? Wqkv[k * 768 + n] : Wqs[k * 512 + (n - 768)];
    WtCat[i] = f2bf(v);
  } else {
    int i = (blk - 4032 - 5120) * 256 + threadIdx.x;
    int n = i >> 8, k = i & 255;
    WtOut[i] = f2bf(Wout[k * 1024 + n]);
  }
}

// ---------------- projection GEMM: [8064,1024] x [1280,1024]^T --------------
__global__ __launch_bounds__(256) void k_gemm_proj(
    const u16* __restrict__ A, const u16* __restrict__ Bt,
    u16* __restrict__ Qp, u16* __restrict__ Kp, u16* __restrict__ Vp,
    u16* __restrict__ Qsb, u16* __restrict__ Ksb)
{
  __shared__ u16 smem[2][128 * 64];           // A/B staging; reused as C[128][128]
  u16* Asm = smem[0];
  u16* Bsm = smem[1];
  int orig = blockIdx.x + blockIdx.y * 63;
  int xcd = orig & 7, slot = orig >> 3;
  int nid = (xcd < 6 ? xcd * 79 : 474 + (xcd - 6) * 78) + slot;
  int mt = (nid / 10) * 128, nt = (nid % 10) * 128;
  int tid = threadIdx.x, lane = tid & 63, w = tid >> 6;
  int wm = w >> 1, wn = w & 1;
  int fr = lane & 15, fq = lane >> 4;
  int srow = w * 32 + (lane >> 3);
  int scol = (lane & 7) * 8;
  f32x4 acc[4][4];
#pragma unroll
  for (int a = 0; a < 4; ++a)
#pragma unroll
    for (int b = 0; b < 4; ++b) acc[a][b] = (f32x4){0.f, 0.f, 0.f, 0.f};

  for (int kt = 0; kt < 1024; kt += 64) {
#pragma unroll
    for (int j = 0; j < 4; ++j) {
      int r = srow + j * 8;
      gload_lds16(A + (size_t)(mt + r) * 1024 + kt + scol, Asm + (size_t)(w * 32 + j * 8) * 64);
      gload_lds16(Bt + (size_t)(nt + r) * 1024 + kt + scol, Bsm + (size_t)(w * 32 + j * 8) * 64);
    }
    __syncthreads();
#pragma unroll
    for (int cs = 0; cs < 2; ++cs) {
      short8 af[4], bf[4];
#pragma unroll
      for (int i = 0; i < 4; ++i) {
        af[i] = *(const short8*)&Asm[(size_t)(wm * 64 + i * 16 + fr) * 64 + cs * 32 + fq * 8];
        bf[i] = *(const short8*)&Bsm[(size_t)(wn * 64 + i * 16 + fr) * 64 + cs * 32 + fq * 8];
      }
      __builtin_amdgcn_s_setprio(1);
#pragma unroll
      for (int mi = 0; mi < 4; ++mi)
#pragma unroll
        for (int ni = 0; ni < 4; ++ni)
          acc[mi][ni] = __builtin_amdgcn_mfma_f32_16x16x32_bf16(af[mi], bf[ni], acc[mi][ni], 0, 0, 0);
      __builtin_amdgcn_s_setprio(0);
    }
    __syncthreads();
  }

  // ---- epilogue: dump acc to LDS C[128][128] (swizzled), sel-pure block ----
  int sel = nt >> 8;                           // 0=q 1=k 2=v 3=qs 4=ks
  float scl = (sel == 0 || sel == 3) ? 0.0625f : 1.0f;
  bool T = (sel == 2);
  u16* Csm = smem[0];                          // 32 KB = [128][128] u16
#pragma unroll
  for (int ni = 0; ni < 4; ++ni) {
#pragma unroll
    for (int mi = 0; mi < 4; ++mi) {
#pragma unroll
      for (int i = 0; i < 4; ++i) {
        int rm = wm * 64 + mi * 16 + fq * 4 + i;     // m-local
        int cn = wn * 64 + ni * 16 + fr;             // n-local
        u16 val = f2bf(acc[mi][ni][i] * scl);
        if (!T) Csm[rm * 128 + (cn ^ ((rm & 7) << 3))] = val;
        else    Csm[cn * 128 + (rm ^ ((cn & 7) << 3))] = val;
      }
    }
  }
  __syncthreads();

  // ---- coalesced packed write-out: 4 row-groups x 2 head-halves ----------
  int t = tid;
#pragma unroll
  for (int rg = 0; rg < 4; ++rg) {
    int row_g = mt + rg * 32;
    int b_ = row_g / TOKP;
    int tok0 = row_g - b_ * TOKP;
    int tile = tok0 >> 5;
#pragma unroll
    for (int g2 = 0; g2 < 2; ++g2) {
      int g = ((nt + g2 * 64) >> 6);
      int h = g & 3;
      int bh = b_ * 4 + h;
      int Lrow, Lcol0;
      if (sel <= 1) {
        Lrow = rg * 32 + (t & 31);
        Lcol0 = g2 * 64 + (t >> 5) * 8;
        short8 v = *(const short8*)&Csm[Lrow * 128 + (Lcol0 ^ ((Lrow & 7) << 3))];
        u16* dst = (sel == 0 ? Qp : Kp) + ((size_t)bh * 63 + tile) * 2048
                   + (t >> 5) * 256 + (t & 31) * 8;
        *(short8*)dst = v;
      } else if (sel == 2) {
        Lrow = g2 * 64 + (t >> 7) * 32 + (t & 31);          // n-local (d)
        Lcol0 = rg * 32 + ((t >> 5) & 3) * 8;               // m-local (tok)
        short8 v = *(const short8*)&Csm[Lrow * 128 + (Lcol0 ^ ((Lrow & 7) << 3))];
        u16* dst = Vp + ((size_t)bh * 63 + tile) * 2048 + (t >> 5) * 256 + (t & 31) * 8;
        *(short8*)dst = v;
      } else {
        int tok_l = t >> 3;
        int tok_g = tok0 + tok_l;
        if (tok_g < NTOK) {
          Lrow = rg * 32 + tok_l;
          Lcol0 = g2 * 64 + (t & 7) * 8;
          short8 v = *(const short8*)&Csm[Lrow * 128 + (Lcol0 ^ ((Lrow & 7) << 3))];
          u16* dst = (sel == 3 ? Qsb : Ksb) + ((size_t)bh * NTOK + tok_g) * 64 + (t & 7) * 8;
          *(short8*)dst = v;
        }
      }
    }
  }
}

// ---------------- block-diagonal self dots (Qs pre-scaled, vectorized) -----
__global__ void k_self(const u16* __restrict__ Qs, const u16* __restrict__ Ks,
                       float* __restrict__ selfS) {
  int blk = blockIdx.x;            // bh*200 + agent
  int bh = blk / 200, a = blk % 200;
  int t = threadIdx.x;
  if (t >= 100) return;
  int ri = t / 10, rj = t % 10;
  const short8* qv = (const short8*)&Qs[((size_t)bh * NTOK + a * 10 + ri) * 64];
  const short8* kv = (const short8*)&Ks[((size_t)bh * NTOK + a * 10 + rj) * 64];
  float s = 0.f;
#pragma unroll
  for (int c = 0; c < 8; ++c) {
    short8 qa = qv[c], kb = kv[c];
#pragma unroll
    for (int j = 0; j < 8; ++j) s += bf2f((u16)qa[j]) * bf2f((u16)kb[j]);
  }
  selfS[(size_t)blk * 100 + t] = s;
}

// ---------------- fused attention v13 + setprio around MFMA clusters -------
__global__ __launch_bounds__(256, 2) void k_attn13(
    const u16* __restrict__ Qp, const u16* __restrict__ Kp,
    const u16* __restrict__ Vp, const float* __restrict__ selfS,
    float* __restrict__ attn, u16* __restrict__ Ob)
{
  __shared__ float s_sum[4][32];
  __shared__ float s_o[4][64][32];   // 32 KB (O combine only)
  int bh = blockIdx.x;
  int qt = blockIdx.y;
  int q0 = qt * 32;
  int tid = threadIdx.x;
  int lane = tid & 63, w = tid >> 6;
  int ql = lane & 31, h = lane >> 5;
  int qg = q0 + ql;
  bool qok = qg < NTOK;
  int qc = qok ? qg : NTOK - 1;
  int lo8 = ql * 8;

  const u16* qbase = Qp + (size_t)bh * PKBH + (size_t)qt * 2048;
  const u16* kbase = Kp + (size_t)bh * PKBH;
  const u16* vbase = Vp + (size_t)bh * PKBH;

  short8 qf[4];
#pragma unroll
  for (int c = 0; c < 4; ++c)
    qf[c] = *(const short8*)&qbase[(c * 2 + h) * 256 + lo8];

  // block-diagonal patch band
  int qa = (qg < 2000) ? (qg / 10) : -1;
  int band_lo = 1 << 30, band_hi = -(1 << 30);
  if (q0 < 2000) {
    int hi_row = (q0 + 31 < 1999) ? q0 + 31 : 1999;
    band_lo = (q0 / 10) * 10;
    band_hi = (hi_row / 10) * 10 + 10;
  }
  const float* sfb = &selfS[(size_t)bh * 20000];

  int t0 = w * 16;
  int t1 = t0 + 16; if (t1 > 63) t1 = 63;

  u32 pb[16][8];                 // packed unnormalized e (bf16 pairs)
  short8 kf[4], kfn[4], vf[4];
  f32x16 oacc0 = {}, oacc1 = {};

  // ====== loop 1: loads + QK + exp + pack + PV (no global stores) ========
#pragma unroll
  for (int c = 0; c < 4; ++c)
    kf[c] = *(const short8*)&kbase[(size_t)t0 * 2048 + (c * 2 + h) * 256 + lo8];
  float ssum = 0.f;
#pragma unroll
  for (int i = 0; i < 16; ++i) {
    int t = t0 + i;
    if (t < t1) {
      int tn = (t + 1 < t1) ? t + 1 : t0;
#pragma unroll
      for (int c = 0; c < 4; ++c)
        vf[c] = *(const short8*)&vbase[(size_t)t * 2048 + (c * 2 + h) * 256 + lo8];
#pragma unroll
      for (int c = 0; c < 4; ++c)
        kfn[c] = *(const short8*)&kbase[(size_t)tn * 2048 + (c * 2 + h) * 256 + lo8];
      f32x16 acc = {};
      __builtin_amdgcn_s_setprio(1);
#pragma unroll
      for (int c = 0; c < 4; ++c)
        acc = __builtin_amdgcn_mfma_f32_32x32x16_bf16(kf[c], qf[c], acc, 0, 0, 0);
      __builtin_amdgcn_s_setprio(0);
      int kt = t * 32;
      float e[16];
      if ((kt < band_hi) && (kt + 32 > band_lo)) {
#pragma unroll
        for (int r = 0; r < 16; ++r) {
          int kc = kt + (r & 3) + 8 * (r >> 2) + 4 * h;
          float sc = acc[r];
          if (qa >= 0 && kc < 2000 && (kc / 10) == qa)
            sc = sfb[qa * 100 + (qg - qa * 10) * 10 + (kc - qa * 10)];
          e[r] = __expf(sc);
        }
      } else {
#pragma unroll
        for (int r = 0; r < 16; ++r) e[r] = __expf(acc[r]);
      }
      if (t == 62) {             // mask k-pad [2009,2016)
#pragma unroll
        for (int r = 0; r < 16; ++r) {
          int kc = kt + (r & 3) + 8 * (r >> 2) + 4 * h;
          if (kc >= NTOK) e[r] = 0.f;
        }
      }
#pragma unroll
      for (int r2 = 0; r2 < 8; ++r2) {
        pb[i][r2] = cvtpk(e[2 * r2], e[2 * r2 + 1]);
        ssum += e[2 * r2] + e[2 * r2 + 1];
      }
      // ---- redistribute pb -> PV B-fragments; PV accumulate ----
      u32 p00 = __shfl_xor(pb[i][0], 32), p01 = __shfl_xor(pb[i][1], 32);
      u32 p10 = __shfl_xor(pb[i][2], 32), p11 = __shfl_xor(pb[i][3], 32);
      u32 p20 = __shfl_xor(pb[i][4], 32), p21 = __shfl_xor(pb[i][5], 32);
      u32 p30 = __shfl_xor(pb[i][6], 32), p31 = __shfl_xor(pb[i][7], 32);
      u32 b0[4], b1[4];
      b0[0] = h ? p10 : pb[i][0];  b0[1] = h ? p11 : pb[i][1];
      b0[2] = h ? pb[i][2] : p00;  b0[3] = h ? pb[i][3] : p01;
      b1[0] = h ? p30 : pb[i][4];  b1[1] = h ? p31 : pb[i][5];
      b1[2] = h ? pb[i][6] : p20;  b1[3] = h ? pb[i][7] : p21;
      short8 B0, B1;
      __builtin_memcpy(&B0, b0, 16);
      __builtin_memcpy(&B1, b1, 16);
      __builtin_amdgcn_s_setprio(1);
      oacc0 = __builtin_amdgcn_mfma_f32_32x32x16_bf16(vf[0], B0, oacc0, 0, 0, 0);
      oacc1 = __builtin_amdgcn_mfma_f32_32x32x16_bf16(vf[2], B0, oacc1, 0, 0, 0);
      oacc0 = __builtin_amdgcn_mfma_f32_32x32x16_bf16(vf[1], B1, oacc0, 0, 0, 0);
      oacc1 = __builtin_amdgcn_mfma_f32_32x32x16_bf16(vf[3], B1, oacc1, 0, 0, 0);
      __builtin_amdgcn_s_setprio(0);
#pragma unroll
      for (int c = 0; c < 4; ++c) kf[c] = kfn[c];
    }
  }
  ssum += __shfl_xor(ssum, 32);
  if (lane < 32) s_sum[w][ql] = ssum;
  __syncthreads();
  float inv = 1.0f / (s_sum[0][ql] + s_sum[1][ql] + s_sum[2][ql] + s_sum[3][ql]);

  // ====== loop 2: direct-from-register store stream ======================
  float* arow = &attn[((size_t)bh * NTOK + qc) * NTOK];
#pragma unroll
  for (int i = 0; i < 16; ++i) {
    int t = t0 + i;
    if (t < t1 && qok) {
      int kt = t * 32;
      float e[16];
#pragma unroll
      for (int r2 = 0; r2 < 8; ++r2) {
        u32 u = pb[i][r2];
        e[2 * r2]     = __uint_as_float(u << 16) * inv;
        e[2 * r2 + 1] = __uint_as_float(u & 0xffff0000u) * inv;
      }
      if (t < 62) {
#pragma unroll
        for (int rq = 0; rq < 4; ++rq) {
          int col0 = kt + 8 * rq + 4 * h;
          *(float4a*)&arow[col0] =
              (float4a){e[4 * rq], e[4 * rq + 1], e[4 * rq + 2], e[4 * rq + 3]};
        }
      } else {
#pragma unroll
        for (int rq = 0; rq < 4; ++rq) {
          int col0 = kt + 8 * rq + 4 * h;
          if (col0 + 3 < NTOK) {
            *(float4a*)&arow[col0] =
                (float4a){e[4 * rq], e[4 * rq + 1], e[4 * rq + 2], e[4 * rq + 3]};
          } else {
#pragma unroll
            for (int j = 0; j < 4; ++j)
              if (col0 + j < NTOK) arow[col0 + j] = e[4 * rq + j];
          }
        }
      }
    }
  }

  // ---- combine partial O across waves via LDS (normalize here) ----
#pragma unroll
  for (int r = 0; r < 16; ++r) {
    int d = (r & 3) + 8 * (r >> 2) + 4 * h;
    s_o[w][d][ql] = oacc0[r];
    s_o[w][d + 32][ql] = oacc1[r];
  }
  __syncthreads();
  {
    int q = tid & 31, dg = tid >> 5;          // 8 d's per thread
    int qg2 = q0 + q;
    if (qg2 < NTOK) {
      float invq = 1.0f / (s_sum[0][q] + s_sum[1][q] + s_sum[2][q] + s_sum[3][q]);
      int b_ = bh >> 2, hd = bh & 3;
      u16* orow = &Ob[((size_t)(b_ * NTOK + qg2)) * 256 + hd * 64 + dg * 8];
      u32 wpk[4];
#pragma unroll
      for (int j = 0; j < 4; ++j) {
        int d = dg * 8 + 2 * j;
        float a = (s_o[0][d][q] + s_o[1][d][q] + s_o[2][d][q] + s_o[3][d][q]) * invq;
        float b = (s_o[0][d + 1][q] + s_o[1][d + 1][q] + s_o[2][d + 1][q] + s_o[3][d + 1][q]) * invq;
        wpk[j] = pk2(a, b);
      }
      *(uint4*)orow = make_uint4(wpk[0], wpk[1], wpk[2], wpk[3]);
    }
  }
}

// ---------------- output GEMM (m97-style): [8036,256] x [1024,256]^T + bias --
__global__ __launch_bounds__(256) void k_gemm_out(
    const u16* __restrict__ A, const u16* __restrict__ Bt,
    const float* __restrict__ bias, float* __restrict__ C)
{
  __shared__ u16 Asm[128 * 64];
  __shared__ u16 Bsm[128 * 64];
  int orig = blockIdx.x + blockIdx.y * 63;
  int xcd = orig & 7, slot = orig >> 3;
  int nid = xcd * 63 + slot;
  int mt = (nid >> 3) * 128, nt = (nid & 7) * 128;
  int tid = threadIdx.x, lane = tid & 63, w = tid >> 6;
  int wm = w >> 1, wn = w & 1;
  int fr = lane & 15, fq = lane >> 4;
  int srow = w * 32 + (lane >> 3);
  int scol = (lane & 7) * 8;
  f32x4 acc[4][4];
#pragma unroll
  for (int a = 0; a < 4; ++a)
#pragma unroll
    for (int b = 0; b < 4; ++b) acc[a][b] = (f32x4){0.f, 0.f, 0.f, 0.f};

  for (int kt = 0; kt < 256; kt += 64) {
#pragma unroll
    for (int j = 0; j < 4; ++j) {
      int r = srow + j * 8;
      int am = mt + r; if (am >= M8) am = 0;
      gload_lds16(A + (size_t)am * 256 + kt + scol, Asm + (size_t)(w * 32 + j * 8) * 64);
      gload_lds16(Bt + (size_t)(nt + r) * 256 + kt + scol, Bsm + (size_t)(w * 32 + j * 8) * 64);
    }
    __syncthreads();
#pragma unroll
    for (int cs = 0; cs < 2; ++cs) {
      short8 af[4], bf[4];
#pragma unroll
      for (int i = 0; i < 4; ++i) {
        af[i] = *(const short8*)&Asm[(size_t)(wm * 64 + i * 16 + fr) * 64 + cs * 32 + fq * 8];
        bf[i] = *(const short8*)&Bsm[(size_t)(wn * 64 + i * 16 + fr) * 64 + cs * 32 + fq * 8];
      }
      __builtin_amdgcn_s_setprio(1);
#pragma unroll
      for (int mi = 0; mi < 4; ++mi)
#pragma unroll
        for (int ni = 0; ni < 4; ++ni)
          acc[mi][ni] = __builtin_amdgcn_mfma_f32_16x16x32_bf16(af[mi], bf[ni], acc[mi][ni], 0, 0, 0);
      __builtin_amdgcn_s_setprio(0);
    }
    __syncthreads();
  }

#pragma unroll
  for (int ni = 0; ni < 4; ++ni) {
    int n = nt + wn * 64 + ni * 16 + fr;
    float bn = bias[n];
#pragma unroll
    for (int mi = 0; mi < 4; ++mi)
#pragma unroll
      for (int i = 0; i < 4; ++i) {
        int m = mt + wm * 64 + mi * 16 + fq * 4 + i;
        if (m < M8) C[(size_t)m * DMOD + n] = acc[mi][ni][i] + bn;
      }
  }
}

extern "C" void kernel_launch(void* const* d_in, const int* in_sizes, int n_in,
                              void* d_out, int out_size, void* d_ws, size_t ws_size,
                              hipStream_t stream) {
  (void)in_sizes; (void)n_in; (void)out_size; (void)ws_size;
  const float* x    = (const float*)d_in[0];
  const float* Wqkv = (const float*)d_in[1];
  const float* Wqs  = (const float*)d_in[2];
  const float* Wout = (const float*)d_in[3];
  const float* bout = (const float*)d_in[4];
  float* out  = (float*)d_out;
  float* attn = out + (size_t)M8 * DMOD;

  char* ws = (char*)d_ws;
  u16*   xb    = (u16*)(ws);                      // 16,515,072 B (padded)
  u16*   WtCat = (u16*)(ws + 16515072);           //  2,621,440
  u16*   WtOut = (u16*)(ws + 19136512);           //    524,288
  u16*   Qp    = (u16*)(ws + 19660800);           //  4,128,768
  u16*   Kp    = (u16*)(ws + 23789568);           //  4,128,768
  u16*   Vp    = (u16*)(ws + 27918336);           //  4,128,768
  u16*   Qsb   = (u16*)(ws + 32047104);           //  4,114,432
  u16*   Ksb   = (u16*)(ws + 36161536);           //  4,114,432
  u16*   Ob    = (u16*)(ws + 40275968);           //  4,114,432
  float* selfS = (float*)(ws + 44390400);         //  1,280,000 (end ~45.7 MB)

  k_convs<<<dim3(4032 + 5120 + 1024), dim3(256), 0, stream>>>(
      x, xb, Wqkv, Wqs, WtCat, Wout, WtOut);
  k_gemm_proj<<<dim3(63, 10), dim3(256), 0, stream>>>(xb, WtCat, Qp, Kp, Vp, Qsb, Ksb);
  k_self<<<dim3(3200), dim3(128), 0, stream>>>(Qsb, Ksb, selfS);
  k_attn13<<<dim3(16, 63), dim3(256), 0, stream>>>(Qp, Kp, Vp, selfS, attn, Ob);
  k_gemm_out<<<dim3(63, 8), dim3(256), 0, stream>>>(Ob, WtOut, bout, out);
}

// Round 18
// 187.399 us; speedup vs baseline: 1.0014x; 1.0014x over previous
//
#include <hip/hip_runtime.h>

typedef unsigned short u16;
typedef unsigned int u32;
typedef short short8 __attribute__((ext_vector_type(8)));
typedef float f32x4 __attribute__((ext_vector_type(4)));
typedef float f32x16 __attribute__((ext_vector_type(16)));
typedef float float4a __attribute__((ext_vector_type(4), aligned(4)));

#define NTOK 2009
#define M8   8036      // 4*2009 (real rows)
#define TOKP 2016      // padded tokens per batch (63*32)
#define M8P  8064      // 4*2016 padded rows
#define DMOD 1024
// packed fragment buffers: [bh][tile(63)][...][256] u16; 2048 u16 per tile
#define PKBH 129024    // 63*2048 u16 per bh

static __device__ __forceinline__ u16 f2bf(float f) {
  unsigned int x = __float_as_uint(f);
  x += 0x7fffu + ((x >> 16) & 1u);
  return (u16)(x >> 16);
}
static __device__ __forceinline__ float bf2f(u16 u) {
  return __uint_as_float((unsigned int)u << 16);
}
static __device__ __forceinline__ u32 pk2(float a, float b) {
  return (u32)f2bf(a) | ((u32)f2bf(b) << 16);
}
static __device__ __forceinline__ u32 cvtpk(float a, float b) {
  u32 d;
  asm("v_cvt_pk_bf16_f32 %0, %1, %2" : "=v"(d) : "v"(a), "v"(b));
  return d;
}
static __device__ __forceinline__ void gload_lds16(const void* g, void* l) {
  __builtin_amdgcn_global_load_lds(
      (const __attribute__((address_space(1))) void*)g,
      (__attribute__((address_space(3))) void*)l, 16, 0, 0);
}

// ---------------- merged converts (one launch); xb padded to [4][2016][1024] --
// x path: 2 float4 in -> 1 uint4 out per thread (16B stores).
__global__ void k_convs(const float* __restrict__ x, u16* __restrict__ xb,
                        const float* __restrict__ Wqkv, const float* __restrict__ Wqs,
                        u16* __restrict__ WtCat,
                        const float* __restrict__ Wout, u16* __restrict__ WtOut) {
  int blk = blockIdx.x;
  if (blk < 4032) {
    int i = blk * 256 + threadIdx.x;          // uint4 index over padded xb
    int b = i / (TOKP * 128);
    int rem = i - b * (TOKP * 128);
    int tok = rem >> 7, g8 = rem & 127;       // 8-float group within row
    uint4 o = make_uint4(0u, 0u, 0u, 0u);
    if (tok < NTOK) {
      const float4* src = (const float4*)x + (size_t)(b * NTOK + tok) * 256 + g8 * 2;
      float4 v0 = src[0], v1 = src[1];
      o.x = (u32)f2bf(v0.x) | ((u32)f2bf(v0.y) << 16);
      o.y = (u32)f2bf(v0.z) | ((u32)f2bf(v0.w) << 16);
      o.z = (u32)f2bf(v1.x) | ((u32)f2bf(v1.y) << 16);
      o.w = (u32)f2bf(v1.z) | ((u32)f2bf(v1.w) << 16);
    }
    ((uint4*)xb)[i] = o;
  } else if (blk < 4032 + 5120) {
    int i = (blk - 4032) * 256 + threadIdx.x;
    int n = i >> 10, k = i & 1023;
    float v = (n < 768) ? Wqkv[k * 768 + n] : Wqs[k * 512 + (n - 768)];
    WtCat[i] = f2bf(v);
  } else {
    int i = (blk - 4032 - 5120) * 256 + threadIdx.x;
    int n = i >> 8, k = i & 255;
    WtOut[i] = f2bf(Wout[k * 1024 + n]);
  }
}

// ---------------- projection GEMM: [8064,1024] x [1280,1024]^T --------------
__global__ __launch_bounds__(256) void k_gemm_proj(
    const u16* __restrict__ A, const u16* __restrict__ Bt,
    u16* __restrict__ Qp, u16* __restrict__ Kp, u16* __restrict__ Vp,
    u16* __restrict__ Qsb, u16* __restrict__ Ksb)
{
  __shared__ u16 smem[2][128 * 64];           // A/B staging; reused as C[128][128]
  u16* Asm = smem[0];
  u16* Bsm = smem[1];
  int orig = blockIdx.x + blockIdx.y * 63;
  int xcd = orig & 7, slot = orig >> 3;
  int nid = (xcd < 6 ? xcd * 79 : 474 + (xcd - 6) * 78) + slot;
  int mt = (nid / 10) * 128, nt = (nid % 10) * 128;
  int tid = threadIdx.x, lane = tid & 63, w = tid >> 6;
  int wm = w >> 1, wn = w & 1;
  int fr = lane & 15, fq = lane >> 4;
  int srow = w * 32 + (lane >> 3);
  int scol = (lane & 7) * 8;
  f32x4 acc[4][4];
#pragma unroll
  for (int a = 0; a < 4; ++a)
#pragma unroll
    for (int b = 0; b < 4; ++b) acc[a][b] = (f32x4){0.f, 0.f, 0.f, 0.f};

  for (int kt = 0; kt < 1024; kt += 64) {
#pragma unroll
    for (int j = 0; j < 4; ++j) {
      int r = srow + j * 8;
      gload_lds16(A + (size_t)(mt + r) * 1024 + kt + scol, Asm + (size_t)(w * 32 + j * 8) * 64);
      gload_lds16(Bt + (size_t)(nt + r) * 1024 + kt + scol, Bsm + (size_t)(w * 32 + j * 8) * 64);
    }
    __syncthreads();
#pragma unroll
    for (int cs = 0; cs < 2; ++cs) {
      short8 af[4], bf[4];
#pragma unroll
      for (int i = 0; i < 4; ++i) {
        af[i] = *(const short8*)&Asm[(size_t)(wm * 64 + i * 16 + fr) * 64 + cs * 32 + fq * 8];
        bf[i] = *(const short8*)&Bsm[(size_t)(wn * 64 + i * 16 + fr) * 64 + cs * 32 + fq * 8];
      }
      __builtin_amdgcn_s_setprio(1);
#pragma unroll
      for (int mi = 0; mi < 4; ++mi)
#pragma unroll
        for (int ni = 0; ni < 4; ++ni)
          acc[mi][ni] = __builtin_amdgcn_mfma_f32_16x16x32_bf16(af[mi], bf[ni], acc[mi][ni], 0, 0, 0);
      __builtin_amdgcn_s_setprio(0);
    }
    __syncthreads();
  }

  // ---- epilogue: dump acc to LDS C[128][128] (swizzled), sel-pure block ----
  int sel = nt >> 8;                           // 0=q 1=k 2=v 3=qs 4=ks
  float scl = (sel == 0 || sel == 3) ? 0.0625f : 1.0f;
  bool T = (sel == 2);
  u16* Csm = smem[0];                          // 32 KB = [128][128] u16
#pragma unroll
  for (int ni = 0; ni < 4; ++ni) {
#pragma unroll
    for (int mi = 0; mi < 4; ++mi) {
#pragma unroll
      for (int i = 0; i < 4; ++i) {
        int rm = wm * 64 + mi * 16 + fq * 4 + i;     // m-local
        int cn = wn * 64 + ni * 16 + fr;             // n-local
        u16 val = f2bf(acc[mi][ni][i] * scl);
        if (!T) Csm[rm * 128 + (cn ^ ((rm & 7) << 3))] = val;
        else    Csm[cn * 128 + (rm ^ ((cn & 7) << 3))] = val;
      }
    }
  }
  __syncthreads();

  // ---- coalesced packed write-out: 4 row-groups x 2 head-halves ----------
  int t = tid;
#pragma unroll
  for (int rg = 0; rg < 4; ++rg) {
    int row_g = mt + rg * 32;
    int b_ = row_g / TOKP;
    int tok0 = row_g - b_ * TOKP;
    int tile = tok0 >> 5;
#pragma unroll
    for (int g2 = 0; g2 < 2; ++g2) {
      int g = ((nt + g2 * 64) >> 6);
      int h = g & 3;
      int bh = b_ * 4 + h;
      int Lrow, Lcol0;
      if (sel <= 1) {
        Lrow = rg * 32 + (t & 31);
        Lcol0 = g2 * 64 + (t >> 5) * 8;
        short8 v = *(const short8*)&Csm[Lrow * 128 + (Lcol0 ^ ((Lrow & 7) << 3))];
        u16* dst = (sel == 0 ? Qp : Kp) + ((size_t)bh * 63 + tile) * 2048
                   + (t >> 5) * 256 + (t & 31) * 8;
        *(short8*)dst = v;
      } else if (sel == 2) {
        Lrow = g2 * 64 + (t >> 7) * 32 + (t & 31);          // n-local (d)
        Lcol0 = rg * 32 + ((t >> 5) & 3) * 8;               // m-local (tok)
        short8 v = *(const short8*)&Csm[Lrow * 128 + (Lcol0 ^ ((Lrow & 7) << 3))];
        u16* dst = Vp + ((size_t)bh * 63 + tile) * 2048 + (t >> 5) * 256 + (t & 31) * 8;
        *(short8*)dst = v;
      } else {
        int tok_l = t >> 3;
        int tok_g = tok0 + tok_l;
        if (tok_g < NTOK) {
          Lrow = rg * 32 + tok_l;
          Lcol0 = g2 * 64 + (t & 7) * 8;
          short8 v = *(const short8*)&Csm[Lrow * 128 + (Lcol0 ^ ((Lrow & 7) << 3))];
          u16* dst = (sel == 3 ? Qsb : Ksb) + ((size_t)bh * NTOK + tok_g) * 64 + (t & 7) * 8;
          *(short8*)dst = v;
        }
      }
    }
  }
}

// ---------------- block-diagonal self dots (Qs pre-scaled, vectorized) -----
__global__ void k_self(const u16* __restrict__ Qs, const u16* __restrict__ Ks,
                       float* __restrict__ selfS) {
  int blk = blockIdx.x;            // bh*200 + agent
  int bh = blk / 200, a = blk % 200;
  int t = threadIdx.x;
  if (t >= 100) return;
  int ri = t / 10, rj = t % 10;
  const short8* qv = (const short8*)&Qs[((size_t)bh * NTOK + a * 10 + ri) * 64];
  const short8* kv = (const short8*)&Ks[((size_t)bh * NTOK + a * 10 + rj) * 64];
  float s = 0.f;
#pragma unroll
  for (int c = 0; c < 8; ++c) {
    short8 qa = qv[c], kb = kv[c];
#pragma unroll
    for (int j = 0; j < 8; ++j) s += bf2f((u16)qa[j]) * bf2f((u16)kb[j]);
  }
  selfS[(size_t)blk * 100 + t] = s;
}

// ---------------- fused attention v13 + setprio around MFMA clusters -------
__global__ __launch_bounds__(256, 2) void k_attn13(
    const u16* __restrict__ Qp, const u16* __restrict__ Kp,
    const u16* __restrict__ Vp, const float* __restrict__ selfS,
    float* __restrict__ attn, u16* __restrict__ Ob)
{
  __shared__ float s_sum[4][32];
  __shared__ float s_o[4][64][32];   // 32 KB (O combine only)
  int bh = blockIdx.x;
  int qt = blockIdx.y;
  int q0 = qt * 32;
  int tid = threadIdx.x;
  int lane = tid & 63, w = tid >> 6;
  int ql = lane & 31, h = lane >> 5;
  int qg = q0 + ql;
  bool qok = qg < NTOK;
  int qc = qok ? qg : NTOK - 1;
  int lo8 = ql * 8;

  const u16* qbase = Qp + (size_t)bh * PKBH + (size_t)qt * 2048;
  const u16* kbase = Kp + (size_t)bh * PKBH;
  const u16* vbase = Vp + (size_t)bh * PKBH;

  short8 qf[4];
#pragma unroll
  for (int c = 0; c < 4; ++c)
    qf[c] = *(const short8*)&qbase[(c * 2 + h) * 256 + lo8];

  // block-diagonal patch band
  int qa = (qg < 2000) ? (qg / 10) : -1;
  int band_lo = 1 << 30, band_hi = -(1 << 30);
  if (q0 < 2000) {
    int hi_row = (q0 + 31 < 1999) ? q0 + 31 : 1999;
    band_lo = (q0 / 10) * 10;
    band_hi = (hi_row / 10) * 10 + 10;
  }
  const float* sfb = &selfS[(size_t)bh * 20000];

  int t0 = w * 16;
  int t1 = t0 + 16; if (t1 > 63) t1 = 63;

  u32 pb[16][8];                 // packed unnormalized e (bf16 pairs)
  short8 kf[4], kfn[4], vf[4];
  f32x16 oacc0 = {}, oacc1 = {};

  // ====== loop 1: loads + QK + exp + pack + PV (no global stores) ========
#pragma unroll
  for (int c = 0; c < 4; ++c)
    kf[c] = *(const short8*)&kbase[(size_t)t0 * 2048 + (c * 2 + h) * 256 + lo8];
  float ssum = 0.f;
#pragma unroll
  for (int i = 0; i < 16; ++i) {
    int t = t0 + i;
    if (t < t1) {
      int tn = (t + 1 < t1) ? t + 1 : t0;
#pragma unroll
      for (int c = 0; c < 4; ++c)
        vf[c] = *(const short8*)&vbase[(size_t)t * 2048 + (c * 2 + h) * 256 + lo8];
#pragma unroll
      for (int c = 0; c < 4; ++c)
        kfn[c] = *(const short8*)&kbase[(size_t)tn * 2048 + (c * 2 + h) * 256 + lo8];
      f32x16 acc = {};
      __builtin_amdgcn_s_setprio(1);
#pragma unroll
      for (int c = 0; c < 4; ++c)
        acc = __builtin_amdgcn_mfma_f32_32x32x16_bf16(kf[c], qf[c], acc, 0, 0, 0);
      __builtin_amdgcn_s_setprio(0);
      int kt = t * 32;
      float e[16];
      if ((kt < band_hi) && (kt + 32 > band_lo)) {
#pragma unroll
        for (int r = 0; r < 16; ++r) {
          int kc = kt + (r & 3) + 8 * (r >> 2) + 4 * h;
          float sc = acc[r];
          if (qa >= 0 && kc < 2000 && (kc / 10) == qa)
            sc = sfb[qa * 100 + (qg - qa * 10) * 10 + (kc - qa * 10)];
          e[r] = __expf(sc);
        }
      } else {
#pragma unroll
        for (int r = 0; r < 16; ++r) e[r] = __expf(acc[r]);
      }
      if (t == 62) {             // mask k-pad [2009,2016)
#pragma unroll
        for (int r = 0; r < 16; ++r) {
          int kc = kt + (r & 3) + 8 * (r >> 2) + 4 * h;
          if (kc >= NTOK) e[r] = 0.f;
        }
      }
#pragma unroll
      for (int r2 = 0; r2 < 8; ++r2) {
        pb[i][r2] = cvtpk(e[2 * r2], e[2 * r2 + 1]);
        ssum += e[2 * r2] + e[2 * r2 + 1];
      }
      // ---- redistribute pb -> PV B-fragments; PV accumulate ----
      u32 p00 = __shfl_xor(pb[i][0], 32), p01 = __shfl_xor(pb[i][1], 32);
      u32 p10 = __shfl_xor(pb[i][2], 32), p11 = __shfl_xor(pb[i][3], 32);
      u32 p20 = __shfl_xor(pb[i][4], 32), p21 = __shfl_xor(pb[i][5], 32);
      u32 p30 = __shfl_xor(pb[i][6], 32), p31 = __shfl_xor(pb[i][7], 32);
      u32 b0[4], b1[4];
      b0[0] = h ? p10 : pb[i][0];  b0[1] = h ? p11 : pb[i][1];
      b0[2] = h ? pb[i][2] : p00;  b0[3] = h ? pb[i][3] : p01;
      b1[0] = h ? p30 : pb[i][4];  b1[1] = h ? p31 : pb[i][5];
      b1[2] = h ? pb[i][6] : p20;  b1[3] = h ? pb[i][7] : p21;
      short8 B0, B1;
      __builtin_memcpy(&B0, b0, 16);
      __builtin_memcpy(&B1, b1, 16);
      __builtin_amdgcn_s_setprio(1);
      oacc0 = __builtin_amdgcn_mfma_f32_32x32x16_bf16(vf[0], B0, oacc0, 0, 0, 0);
      oacc1 = __builtin_amdgcn_mfma_f32_32x32x16_bf16(vf[2], B0, oacc1, 0, 0, 0);
      oacc0 = __builtin_amdgcn_mfma_f32_32x32x16_bf16(vf[1], B1, oacc0, 0, 0, 0);
      oacc1 = __builtin_amdgcn_mfma_f32_32x32x16_bf16(vf[3], B1, oacc1, 0, 0, 0);
      __builtin_amdgcn_s_setprio(0);
#pragma unroll
      for (int c = 0; c < 4; ++c) kf[c] = kfn[c];
    }
  }
  ssum += __shfl_xor(ssum, 32);
  if (lane < 32) s_sum[w][ql] = ssum;
  __syncthreads();
  float inv = 1.0f / (s_sum[0][ql] + s_sum[1][ql] + s_sum[2][ql] + s_sum[3][ql]);

  // ====== loop 2: direct-from-register store stream ======================
  float* arow = &attn[((size_t)bh * NTOK + qc) * NTOK];
#pragma unroll
  for (int i = 0; i < 16; ++i) {
    int t = t0 + i;
    if (t < t1 && qok) {
      int kt = t * 32;
      float e[16];
#pragma unroll
      for (int r2 = 0; r2 < 8; ++r2) {
        u32 u = pb[i][r2];
        e[2 * r2]     = __uint_as_float(u << 16) * inv;
        e[2 * r2 + 1] = __uint_as_float(u & 0xffff0000u) * inv;
      }
      if (t < 62) {
#pragma unroll
        for (int rq = 0; rq < 4; ++rq) {
          int col0 = kt + 8 * rq + 4 * h;
          *(float4a*)&arow[col0] =
              (float4a){e[4 * rq], e[4 * rq + 1], e[4 * rq + 2], e[4 * rq + 3]};
        }
      } else {
#pragma unroll
        for (int rq = 0; rq < 4; ++rq) {
          int col0 = kt + 8 * rq + 4 * h;
          if (col0 + 3 < NTOK) {
            *(float4a*)&arow[col0] =
                (float4a){e[4 * rq], e[4 * rq + 1], e[4 * rq + 2], e[4 * rq + 3]};
          } else {
#pragma unroll
            for (int j = 0; j < 4; ++j)
              if (col0 + j < NTOK) arow[col0 + j] = e[4 * rq + j];
          }
        }
      }
    }
  }

  // ---- combine partial O across waves via LDS (normalize here) ----
#pragma unroll
  for (int r = 0; r < 16; ++r) {
    int d = (r & 3) + 8 * (r >> 2) + 4 * h;
    s_o[w][d][ql] = oacc0[r];
    s_o[w][d + 32][ql] = oacc1[r];
  }
  __syncthreads();
  {
    int q = tid & 31, dg = tid >> 5;          // 8 d's per thread
    int qg2 = q0 + q;
    if (qg2 < NTOK) {
      float invq = 1.0f / (s_sum[0][q] + s_sum[1][q] + s_sum[2][q] + s_sum[3][q]);
      int b_ = bh >> 2, hd = bh & 3;
      u16* orow = &Ob[((size_t)(b_ * NTOK + qg2)) * 256 + hd * 64 + dg * 8];
      u32 wpk[4];
#pragma unroll
      for (int j = 0; j < 4; ++j) {
        int d = dg * 8 + 2 * j;
        float a = (s_o[0][d][q] + s_o[1][d][q] + s_o[2][d][q] + s_o[3][d][q]) * invq;
        float b = (s_o[0][d + 1][q] + s_o[1][d + 1][q] + s_o[2][d + 1][q] + s_o[3][d + 1][q]) * invq;
        wpk[j] = pk2(a, b);
      }
      *(uint4*)orow = make_uint4(wpk[0], wpk[1], wpk[2], wpk[3]);
    }
  }
}

// ---------------- output GEMM (m97-style): [8036,256] x [1024,256]^T + bias --
__global__ __launch_bounds__(256) void k_gemm_out(
    const u16* __restrict__ A, const u16* __restrict__ Bt,
    const float* __restrict__ bias, float* __restrict__ C)
{
  __shared__ u16 Asm[128 * 64];
  __shared__ u16 Bsm[128 * 64];
  int orig = blockIdx.x + blockIdx.y * 63;
  int xcd = orig & 7, slot = orig >> 3;
  int nid = xcd * 63 + slot;
  int mt = (nid >> 3) * 128, nt = (nid & 7) * 128;
  int tid = threadIdx.x, lane = tid & 63, w = tid >> 6;
  int wm = w >> 1, wn = w & 1;
  int fr = lane & 15, fq = lane >> 4;
  int srow = w * 32 + (lane >> 3);
  int scol = (lane & 7) * 8;
  f32x4 acc[4][4];
#pragma unroll
  for (int a = 0; a < 4; ++a)
#pragma unroll
    for (int b = 0; b < 4; ++b) acc[a][b] = (f32x4){0.f, 0.f, 0.f, 0.f};

  for (int kt = 0; kt < 256; kt += 64) {
#pragma unroll
    for (int j = 0; j < 4; ++j) {
      int r = srow + j * 8;
      int am = mt + r; if (am >= M8) am = 0;
      gload_lds16(A + (size_t)am * 256 + kt + scol, Asm + (size_t)(w * 32 + j * 8) * 64);
      gload_lds16(Bt + (size_t)(nt + r) * 256 + kt + scol, Bsm + (size_t)(w * 32 + j * 8) * 64);
    }
    __syncthreads();
#pragma unroll
    for (int cs = 0; cs < 2; ++cs) {
      short8 af[4], bf[4];
#pragma unroll
      for (int i = 0; i < 4; ++i) {
        af[i] = *(const short8*)&Asm[(size_t)(wm * 64 + i * 16 + fr) * 64 + cs * 32 + fq * 8];
        bf[i] = *(const short8*)&Bsm[(size_t)(wn * 64 + i * 16 + fr) * 64 + cs * 32 + fq * 8];
      }
      __builtin_amdgcn_s_setprio(1);
#pragma unroll
      for (int mi = 0; mi < 4; ++mi)
#pragma unroll
        for (int ni = 0; ni < 4; ++ni)
          acc[mi][ni] = __builtin_amdgcn_mfma_f32_16x16x32_bf16(af[mi], bf[ni], acc[mi][ni], 0, 0, 0);
      __builtin_amdgcn_s_setprio(0);
    }
    __syncthreads();
  }

#pragma unroll
  for (int ni = 0; ni < 4; ++ni) {
    int n = nt + wn * 64 + ni * 16 + fr;
    float bn = bias[n];
#pragma unroll
    for (int mi = 0; mi < 4; ++mi)
#pragma unroll
      for (int i = 0; i < 4; ++i) {
        int m = mt + wm * 64 + mi * 16 + fq * 4 + i;
        if (m < M8) C[(size_t)m * DMOD + n] = acc[mi][ni][i] + bn;
      }
  }
}

extern "C" void kernel_launch(void* const* d_in, const int* in_sizes, int n_in,
                              void* d_out, int out_size, void* d_ws, size_t ws_size,
                              hipStream_t stream) {
  (void)in_sizes; (void)n_in; (void)out_size; (void)ws_size;
  const float* x    = (const float*)d_in[0];
  const float* Wqkv = (const float*)d_in[1];
  const float* Wqs  = (const float*)d_in[2];
  const float* Wout = (const float*)d_in[3];
  const float* bout = (const float*)d_in[4];
  float* out  = (float*)d_out;
  float* attn = out + (size_t)M8 * DMOD;

  char* ws = (char*)d_ws;
  u16*   xb    = (u16*)(ws);                      // 16,515,072 B (padded)
  u16*   WtCat = (u16*)(ws + 16515072);           //  2,621,440
  u16*   WtOut = (u16*)(ws + 19136512);           //    524,288
  u16*   Qp    = (u16*)(ws + 19660800);           //  4,128,768
  u16*   Kp    = (u16*)(ws + 23789568);           //  4,128,768
  u16*   Vp    = (u16*)(ws + 27918336);           //  4,128,768
  u16*   Qsb   = (u16*)(ws + 32047104);           //  4,114,432
  u16*   Ksb   = (u16*)(ws + 36161536);           //  4,114,432
  u16*   Ob    = (u16*)(ws + 40275968);           //  4,114,432
  float* selfS = (float*)(ws + 44390400);         //  1,280,000 (end ~45.7 MB)

  k_convs<<<dim3(4032 + 5120 + 1024), dim3(256), 0, stream>>>(
      x, xb, Wqkv, Wqs, WtCat, Wout, WtOut);
  k_gemm_proj<<<dim3(63, 10), dim3(256), 0, stream>>>(xb, WtCat, Qp, Kp, Vp, Qsb, Ksb);
  k_self<<<dim3(3200), dim3(128), 0, stream>>>(Qsb, Ksb, selfS);
  k_attn13<<<dim3(16, 63), dim3(256), 0, stream>>>(Qp, Kp, Vp, selfS, attn, Ob);
  k_gemm_out<<<dim3(63, 8), dim3(256), 0, stream>>>(Ob, WtOut, bout, out);
}